// Round 18
// baseline (125.134 us; speedup 1.0000x reference)
//
#include <hip/hip_runtime.h>
#include <hip/hip_bf16.h>
#include <math.h>

#define T_SEQ 2048
#define DH 64
#define H 16
#define DIM 1024
#define D3 3072
#define QBLK 128
#define SMAX 12.0f
#define L2E 1.442695041f

typedef __attribute__((ext_vector_type(8))) short short8;
typedef __attribute__((ext_vector_type(4))) short short4v;
typedef __attribute__((ext_vector_type(4))) float f32x4;
typedef unsigned short ushort_t;
typedef unsigned int uint_t;

// K=16 bf16 MFMA — guard only in the DEVICE pass (r16 lesson).
#if defined(__HIP_DEVICE_COMPILE__)
#if __has_builtin(__builtin_amdgcn_mfma_f32_16x16x16bf16_1k)
#define MFMA16(a, b, c) __builtin_amdgcn_mfma_f32_16x16x16bf16_1k((a), (b), (c), 0, 0, 0)
#elif __has_builtin(__builtin_amdgcn_mfma_f32_16x16x16_bf16)
#define MFMA16(a, b, c) __builtin_amdgcn_mfma_f32_16x16x16_bf16((a), (b), (c), 0, 0, 0)
#else
#error "no 16x16x16 bf16 MFMA builtin on device"
#endif
#else
#define MFMA16(a, b, c) (c)
#endif

#define AS1 __attribute__((address_space(1)))
#define AS3 __attribute__((address_space(3)))

__device__ inline ushort_t f2bf(float f) {
    union { float f; uint_t u; } v; v.f = f;
    const uint_t u = v.u;
    return (ushort_t)((u + 0x7FFFu + ((u >> 16) & 1u)) >> 16);
}

// ---------------------------------------------------------------------------
// Merged preprocessing (verbatim r15-verified).
// ---------------------------------------------------------------------------
__global__ __launch_bounds__(256) void prep(
    const float* __restrict__ x, ushort_t* __restrict__ xb,
    const float* __restrict__ w_qkv, ushort_t* __restrict__ wqT,
    const float* __restrict__ w_out, ushort_t* __restrict__ woT) {
    __shared__ float t[32][33];
    const int bx = blockIdx.x;
    if (bx < 2048) {
        const int i = bx * 256 + threadIdx.x;
        const float4 v0 = ((const float4*)x)[(size_t)i * 2];
        const float4 v1 = ((const float4*)x)[(size_t)i * 2 + 1];
        uint4 p;
        p.x = (uint_t)f2bf(v0.x) | ((uint_t)f2bf(v0.y) << 16);
        p.y = (uint_t)f2bf(v0.z) | ((uint_t)f2bf(v0.w) << 16);
        p.z = (uint_t)f2bf(v1.x) | ((uint_t)f2bf(v1.y) << 16);
        p.w = (uint_t)f2bf(v1.z) | ((uint_t)f2bf(v1.w) << 16);
        ((uint4*)xb)[i] = p;
        return;
    }
    const float* w; ushort_t* wT; int K, N, n0, k0;
    if (bx < 5120) {
        const int l = bx - 2048;
        w = w_qkv; wT = wqT; K = DIM; N = D3;
        n0 = (l % 96) * 32; k0 = (l / 96) * 32;
    } else {
        const int l = bx - 5120;
        w = w_out; wT = woT; K = DIM; N = DIM;
        n0 = (l % 32) * 32; k0 = (l / 32) * 32;
    }
    const int tx = threadIdx.x & 31;
    const int ty = threadIdx.x >> 5;
#pragma unroll
    for (int i = 0; i < 4; i++)
        t[ty + 8 * i][tx] = w[(size_t)(k0 + ty + 8 * i) * N + n0 + tx];
    __syncthreads();
#pragma unroll
    for (int i = 0; i < 4; i++)
        wT[(size_t)(n0 + ty + 8 * i) * K + k0 + tx] = f2bf(t[tx][ty + 8 * i]);
}

// ---------------------------------------------------------------------------
// bf16 head transpose (K only): in [bh, 64, 2048] -> out [bh, 2048, 64].
// ---------------------------------------------------------------------------
__global__ void transpose_head_k(const ushort_t* __restrict__ kin, ushort_t* __restrict__ kout) {
    __shared__ ushort_t t[32][33];
    const int tx = threadIdx.x & 31;
    const int ty = threadIdx.x >> 5;
    const int t0 = blockIdx.x * 32;
    const int d0 = blockIdx.y * 32;
    const int bh = blockIdx.z;
    const size_t base = (size_t)bh * DH * T_SEQ;
#pragma unroll
    for (int i = 0; i < 4; i++)
        t[ty + 8 * i][tx] = kin[base + (size_t)(d0 + ty + 8 * i) * T_SEQ + t0 + tx];
    __syncthreads();
#pragma unroll
    for (int i = 0; i < 4; i++)
        kout[base + (size_t)(t0 + ty + 8 * i) * DH + d0 + tx] = t[tx][ty + 8 * i];
}

// ---------------------------------------------------------------------------
// bf16 MFMA GEMM (verbatim r13/r15-verified). 128x128 tile, XCD swizzle.
// ---------------------------------------------------------------------------
template <int NN, int EPI>
__global__ __launch_bounds__(256) void gemm_bf16(
    const ushort_t* __restrict__ A, const ushort_t* __restrict__ Bt,
    float* __restrict__ C, ushort_t* __restrict__ qTt,
    ushort_t* __restrict__ kTt, ushort_t* __restrict__ vTt) {
    __shared__ short Sh[16384];
    short* As = Sh;
    short* Bs = Sh + 8192;
    const int tid = threadIdx.x;
    const int lane = tid & 63;
    const int l15 = lane & 15;
    const int l4 = lane >> 4;
    const int wid = tid >> 6;
    const int wr = wid >> 1;
    const int wc = wid & 1;
    const int nwg = gridDim.x * gridDim.y;
    const int lin = blockIdx.y * gridDim.x + blockIdx.x;
    const int swz = (lin & 7) * (nwg >> 3) + (lin >> 3);
    const int col0 = (swz % gridDim.x) * 128;
    const int row0 = (swz / gridDim.x) * 128;

    f32x4 acc[4][4];
#pragma unroll
    for (int mi = 0; mi < 4; mi++)
#pragma unroll
        for (int ni = 0; ni < 4; ni++) acc[mi][ni] = (f32x4)0.f;

    const int ldsbase = (tid & 192) * 8;

    for (int kt = 0; kt < 16; kt++) {
        const int k0 = kt * 64;
        if (kt) __syncthreads();
#pragma unroll
        for (int it = 0; it < 4; it++) {
            const int chunk = it * 256 + tid;
            const int row = chunk >> 3;
            const int c = chunk & 7;
            const int csrc = c ^ (row & 7);
            const ushort_t* ga = A + (size_t)(row0 + row) * 1024 + k0 + csrc * 8;
            __builtin_amdgcn_global_load_lds(
                (const AS1 void*)ga, (AS3 void*)(As + it * 2048 + ldsbase), 16, 0, 0);
            const ushort_t* gb = Bt + (size_t)(col0 + row) * 1024 + k0 + csrc * 8;
            __builtin_amdgcn_global_load_lds(
                (const AS1 void*)gb, (AS3 void*)(Bs + it * 2048 + ldsbase), 16, 0, 0);
        }
        __syncthreads();

#pragma unroll
        for (int ks = 0; ks < 2; ks++) {
            short8 af[4], bf[4];
#pragma unroll
            for (int mi = 0; mi < 4; mi++) {
                const int row = wr * 64 + mi * 16 + l15;
                const int c = (ks * 4 + l4) ^ (row & 7);
                af[mi] = *(const short8*)(As + row * 64 + c * 8);
            }
#pragma unroll
            for (int ni = 0; ni < 4; ni++) {
                const int row = wc * 64 + ni * 16 + l15;
                const int c = (ks * 4 + l4) ^ (row & 7);
                bf[ni] = *(const short8*)(Bs + row * 64 + c * 8);
            }
#pragma unroll
            for (int mi = 0; mi < 4; mi++)
#pragma unroll
                for (int ni = 0; ni < 4; ni++)
                    acc[mi][ni] = __builtin_amdgcn_mfma_f32_16x16x32_bf16(
                        af[mi], bf[ni], acc[mi][ni], 0, 0, 0);
        }
    }

    if (EPI == 0) {
#pragma unroll
        for (int mi = 0; mi < 4; mi++)
#pragma unroll
            for (int ni = 0; ni < 4; ni++) {
                const int col = col0 + wc * 64 + ni * 16 + l15;
#pragma unroll
                for (int reg = 0; reg < 4; reg++) {
                    const int row = row0 + wr * 64 + mi * 16 + l4 * 4 + reg;
                    C[(size_t)row * NN + col] = acc[mi][ni][reg];
                }
            }
    } else {
        __syncthreads();
#pragma unroll
        for (int ni = 0; ni < 4; ni++) {
            const int col = wc * 64 + ni * 16 + l15;
            const int gcol = col0 + col;
            const float sc = ((gcol % 48) < 16) ? 0.125f : 1.0f;  // q pre-scale
#pragma unroll
            for (int mi = 0; mi < 4; mi++)
#pragma unroll
                for (int reg = 0; reg < 4; reg++) {
                    const int row = wr * 64 + mi * 16 + l4 * 4 + reg;
                    Sh[col * 128 + (row ^ ((col & 7) << 3))] =
                        (short)f2bf(acc[mi][ni][reg] * sc);
                }
        }
        __syncthreads();
        const int b = row0 >> 11;
        const int tbase = row0 & 2047;
#pragma unroll
        for (int i = 0; i < 8; i++) {
            const int chunk = tid + 256 * i;
            const int col = chunk >> 4;
            const int r8 = chunk & 15;
            const short8 v =
                *(const short8*)(Sh + col * 128 + ((r8 * 8) ^ ((col & 7) << 3)));
            const int gcol = col0 + col;
            const int d = gcol / 48;
            const int rem = gcol % 48;
            const int kk = rem / 16;
            const int hh = rem % 16;
            ushort_t* dst = (kk == 0) ? qTt : (kk == 1) ? kTt : vTt;
            *(short8*)(dst + (((size_t)b * H + hh) * DH + d) * T_SEQ + tbase + r8 * 8) = v;
        }
    }
}

// ---------------------------------------------------------------------------
// MFMA flash attention, fixed-max softmax, swapped QK^T, P fully in-register
// (r17-verified math). NEW vs r17: 4 waves x 32 q-rows (two register-level
// q-groups per wave sharing every kb/vb LDS load — pure reg duplication, no
// LDS P buffer exists to race). Staging = r7-verified 2-pass 256-thread
// pattern; epilogue = r11-verified 32-row store.
// qTt pre-scaled 1/8 [b,h,d,t]; kT [b,h,t,64]; vTt [b,h,64,t].
// ---------------------------------------------------------------------------
__global__ __launch_bounds__(256) void attn_mfma(
    const ushort_t* __restrict__ qTt, const ushort_t* __restrict__ kT,
    const ushort_t* __restrict__ vTt, ushort_t* __restrict__ outB) {
    const int lin = blockIdx.z * 256 + blockIdx.y * 16 + blockIdx.x;
    const int swz = (lin & 7) * 64 + (lin >> 3);
    const int qt = swz & 15;
    const int hh = (swz >> 4) & 15;
    const int b  = swz >> 8;
    const int tid = threadIdx.x;       // 0..255
    const int lane = tid & 63;
    const int wid = tid >> 6;          // 0..3
    const int l15 = lane & 15;
    const int l4 = lane >> 4;

    __shared__ short Ks[2][2][4096];   // [buf][half][64 t x 64 d]
    __shared__ short Vs[2][2][4096];   // [buf][half][64 d x 64 t]

    const size_t hb  = ((size_t)b * H + hh) * T_SEQ * DH;
    const size_t hbT = ((size_t)b * H + hh) * (size_t)DH * T_SEQ;

    // Q fragments: 2 groups x 16 rows per wave, gathered from [b,h,d,t]
    short8 qa[2][2];
#pragma unroll
    for (int mi = 0; mi < 2; mi++) {
        const ushort_t* qb = qTt + hbT + (size_t)(qt * QBLK + wid * 32 + mi * 16 + l15);
#pragma unroll
        for (int ks = 0; ks < 2; ks++)
#pragma unroll
            for (int j = 0; j < 8; j++)
                qa[mi][ks][j] = (short)qb[(size_t)(ks * 32 + l4 * 8 + j) * T_SEQ];
    }

    f32x4 o[2][4];
    float lsum[2];
#pragma unroll
    for (int mi = 0; mi < 2; mi++) {
        lsum[mi] = 0.f;
#pragma unroll
        for (int nd = 0; nd < 4; nd++) o[mi][nd] = (f32x4)0.f;
    }

    const int ldsoff = (tid & 192) * 8;

    // r7-verified 2-pass staging (256 threads cover a 64x64 tile)
    auto stage1 = [&](short* Kdst, short* Vdst, int t0) {
#pragma unroll
        for (int it = 0; it < 2; it++) {
            const int chunk = it * 256 + tid;
            const int row = chunk >> 3;
            const int cs = (chunk & 7) ^ (row & 7);
            __builtin_amdgcn_global_load_lds(
                (const AS1 void*)(kT + hb + (size_t)(t0 + row) * DH + cs * 8),
                (AS3 void*)(Kdst + it * 2048 + ldsoff), 16, 0, 0);
            __builtin_amdgcn_global_load_lds(
                (const AS1 void*)(vTt + hbT + (size_t)row * T_SEQ + t0 + cs * 8),
                (AS3 void*)(Vdst + it * 2048 + ldsoff), 16, 0, 0);
        }
    };

    stage1(&Ks[0][0][0], &Vs[0][0][0], 0);
    stage1(&Ks[0][1][0], &Vs[0][1][0], 64);
    __syncthreads();
    int cur = 0;

    for (int jt2 = 0; jt2 < T_SEQ / 128; jt2++) {
        if (jt2 + 1 < T_SEQ / 128) {
            stage1(&Ks[cur ^ 1][0][0], &Vs[cur ^ 1][0][0], (jt2 + 1) * 128);
            stage1(&Ks[cur ^ 1][1][0], &Vs[cur ^ 1][1][0], (jt2 + 1) * 128 + 64);
        }

#pragma unroll
        for (int half = 0; half < 2; half++) {
            const short* Kb = &Ks[cur][half][0];
            const short* Vb = &Vs[cur][half][0];

            // ---- S^T = K Q^T, both q-groups share each kb load ----------
            f32x4 st[2][4];
#pragma unroll
            for (int mi = 0; mi < 2; mi++)
#pragma unroll
                for (int ni = 0; ni < 4; ni++) st[mi][ni] = (f32x4)0.f;
#pragma unroll
            for (int ks = 0; ks < 2; ks++) {
                short8 kb[4];
#pragma unroll
                for (int ni = 0; ni < 4; ni++) {
                    const int row = ni * 16 + l15;
                    const int rc = (ks * 4 + l4) ^ (row & 7);
                    kb[ni] = *(const short8*)(Kb + row * 64 + rc * 8);
                }
                __builtin_amdgcn_s_setprio(1);
#pragma unroll
                for (int ni = 0; ni < 4; ni++) {
                    st[0][ni] = __builtin_amdgcn_mfma_f32_16x16x32_bf16(
                        kb[ni], qa[0][ks], st[0][ni], 0, 0, 0);
                    st[1][ni] = __builtin_amdgcn_mfma_f32_16x16x32_bf16(
                        kb[ni], qa[1][ks], st[1][ni], 0, 0, 0);
                }
                __builtin_amdgcn_s_setprio(0);
            }

            // ---- P in-register: exp, lsum, cvt_pk -> PV A-frags ----------
            short4v pa[2][4];
#pragma unroll
            for (int mi = 0; mi < 2; mi++)
#pragma unroll
                for (int ni = 0; ni < 4; ni++) {
                    float p0 = __builtin_amdgcn_exp2f(__builtin_fmaf(st[mi][ni][0], L2E, -SMAX * L2E));
                    float p1 = __builtin_amdgcn_exp2f(__builtin_fmaf(st[mi][ni][1], L2E, -SMAX * L2E));
                    float p2 = __builtin_amdgcn_exp2f(__builtin_fmaf(st[mi][ni][2], L2E, -SMAX * L2E));
                    float p3 = __builtin_amdgcn_exp2f(__builtin_fmaf(st[mi][ni][3], L2E, -SMAX * L2E));
                    lsum[mi] += (p0 + p1) + (p2 + p3);
                    uint_t lo, hi;
                    asm("v_cvt_pk_bf16_f32 %0, %1, %2" : "=v"(lo) : "v"(p0), "v"(p1));
                    asm("v_cvt_pk_bf16_f32 %0, %1, %2" : "=v"(hi) : "v"(p2), "v"(p3));
                    union { uint_t u[2]; short4v s; } cv;
                    cv.u[0] = lo; cv.u[1] = hi;
                    pa[mi][ni] = cv.s;
                }

            // ---- O += P V via K=16 MFMAs, vb shared by both groups -------
#pragma unroll
            for (int ni = 0; ni < 4; ni++) {
                short4v vb[4];
#pragma unroll
                for (int nd = 0; nd < 4; nd++) {
                    const int row = nd * 16 + l15;
                    const int ch = (2 * ni + (l4 >> 1)) ^ (row & 7);
                    vb[nd] = *(const short4v*)(Vb + row * 64 + ch * 8 + (l4 & 1) * 4);
                }
                __builtin_amdgcn_s_setprio(1);
#pragma unroll
                for (int nd = 0; nd < 4; nd++) {
                    o[0][nd] = MFMA16(pa[0][ni], vb[nd], o[0][nd]);
                    o[1][nd] = MFMA16(pa[1][ni], vb[nd], o[1][nd]);
                }
                __builtin_amdgcn_s_setprio(0);
            }
        }

        __syncthreads();
        cur ^= 1;
    }

    // ---- epilogue: per-group lsum reduce, normalize, stage 32 rows, store
    short* Pt = ((short*)Ks) + wid * 2048;   // Ks dead after final barrier
#pragma unroll
    for (int mi = 0; mi < 2; mi++) {
        float tsum = lsum[mi];
        tsum += __shfl_xor(tsum, 16);
        tsum += __shfl_xor(tsum, 32);
#pragma unroll
        for (int reg = 0; reg < 4; reg++) {
            const int row = l4 * 4 + reg;
            const float inv = 1.0f / __shfl(tsum, row);
#pragma unroll
            for (int nd = 0; nd < 4; nd++)
                Pt[(mi * 16 + row) * 64 + nd * 16 + l15] =
                    (short)f2bf(o[mi][nd][reg] * inv);
        }
    }
    __syncthreads();
#pragma unroll
    for (int i = 0; i < 4; i++) {
        const int chunk = lane + 64 * i;     // 0..255
        const int row = chunk >> 3;          // 0..31
        const int c8 = (chunk & 7) * 8;
        const short8 vv = *(const short8*)(Pt + row * 64 + c8);
        *(short8*)(outB +
                   ((size_t)b * T_SEQ + (size_t)qt * QBLK + wid * 32 + row) * DIM +
                   hh * DH + c8) = vv;
    }
}

extern "C" void kernel_launch(void* const* d_in, const int* in_sizes, int n_in,
                              void* d_out, int out_size, void* d_ws, size_t ws_size,
                              hipStream_t stream) {
    const float* x     = (const float*)d_in[0];
    const float* w_qkv = (const float*)d_in[1];
    const float* w_out = (const float*)d_in[2];
    float* out = (float*)d_out;

    const size_t M = 4096;
    ushort_t* xb    = (ushort_t*)d_ws;                  // 4M shorts
    ushort_t* wqT   = xb + M * DIM;                     // 3M
    ushort_t* woT   = wqT + (size_t)D3 * DIM;           // 1M
    ushort_t* qTt   = woT + (size_t)DIM * DIM;          // 4M  [b,h,d,t] (q/8)
    ushort_t* kTt   = qTt + M * DIM;                    // 4M  [b,h,d,t]
    ushort_t* vTt   = kTt + M * DIM;                    // 4M  [b,h,d,t]
    ushort_t* kB    = vTt + M * DIM;                    // 4M  [b,h,t,d]
    ushort_t* attnB = kB + M * DIM;                     // 4M  [4096,1024]

    prep<<<dim3(6144), dim3(256), 0, stream>>>(x, xb, w_qkv, wqT, w_out, woT);

    gemm_bf16<D3, 1><<<dim3(D3 / 128, M / 128), dim3(256), 0, stream>>>(
        xb, wqT, nullptr, qTt, kTt, vTt);

    transpose_head_k<<<dim3(T_SEQ / 32, DH / 32, 32), dim3(256), 0, stream>>>(
        kTt, kB);

    attn_mfma<<<dim3(16, 16, 2), dim3(256), 0, stream>>>(
        qTt, kB, vTt, attnB);

    gemm_bf16<DIM, 0><<<dim3(DIM / 128, M / 128), dim3(256), 0, stream>>>(
        attnB, woT, out, nullptr, nullptr, nullptr);
}

// Round 19
// 121.210 us; speedup vs baseline: 1.0324x; 1.0324x over previous
//
#include <hip/hip_runtime.h>
#include <hip/hip_bf16.h>
#include <math.h>

#define T_SEQ 2048
#define DH 64
#define H 16
#define DIM 1024
#define D3 3072
#define QBLK 128
#define SMAX 12.0f
#define L2E 1.442695041f

typedef __attribute__((ext_vector_type(8))) short short8;
typedef __attribute__((ext_vector_type(4))) short short4v;
typedef __attribute__((ext_vector_type(4))) float f32x4;
typedef unsigned short ushort_t;
typedef unsigned int uint_t;

// K=16 bf16 MFMA — guard only in the DEVICE pass (r16 lesson).
#if defined(__HIP_DEVICE_COMPILE__)
#if __has_builtin(__builtin_amdgcn_mfma_f32_16x16x16bf16_1k)
#define MFMA16(a, b, c) __builtin_amdgcn_mfma_f32_16x16x16bf16_1k((a), (b), (c), 0, 0, 0)
#elif __has_builtin(__builtin_amdgcn_mfma_f32_16x16x16_bf16)
#define MFMA16(a, b, c) __builtin_amdgcn_mfma_f32_16x16x16_bf16((a), (b), (c), 0, 0, 0)
#else
#error "no 16x16x16 bf16 MFMA builtin on device"
#endif
#else
#define MFMA16(a, b, c) (c)
#endif

#define AS1 __attribute__((address_space(1)))
#define AS3 __attribute__((address_space(3)))

__device__ inline ushort_t f2bf(float f) {
    union { float f; uint_t u; } v; v.f = f;
    const uint_t u = v.u;
    return (ushort_t)((u + 0x7FFFu + ((u >> 16) & 1u)) >> 16);
}

// ---------------------------------------------------------------------------
// Merged preprocessing (verbatim r15-verified): blocks [0,2048) cast x;
// [2048,5120) transpose w_qkv; [5120,6144) transpose w_out.
// ---------------------------------------------------------------------------
__global__ __launch_bounds__(256) void prep(
    const float* __restrict__ x, ushort_t* __restrict__ xb,
    const float* __restrict__ w_qkv, ushort_t* __restrict__ wqT,
    const float* __restrict__ w_out, ushort_t* __restrict__ woT) {
    __shared__ float t[32][33];
    const int bx = blockIdx.x;
    if (bx < 2048) {
        const int i = bx * 256 + threadIdx.x;
        const float4 v0 = ((const float4*)x)[(size_t)i * 2];
        const float4 v1 = ((const float4*)x)[(size_t)i * 2 + 1];
        uint4 p;
        p.x = (uint_t)f2bf(v0.x) | ((uint_t)f2bf(v0.y) << 16);
        p.y = (uint_t)f2bf(v0.z) | ((uint_t)f2bf(v0.w) << 16);
        p.z = (uint_t)f2bf(v1.x) | ((uint_t)f2bf(v1.y) << 16);
        p.w = (uint_t)f2bf(v1.z) | ((uint_t)f2bf(v1.w) << 16);
        ((uint4*)xb)[i] = p;
        return;
    }
    const float* w; ushort_t* wT; int K, N, n0, k0;
    if (bx < 5120) {
        const int l = bx - 2048;
        w = w_qkv; wT = wqT; K = DIM; N = D3;
        n0 = (l % 96) * 32; k0 = (l / 96) * 32;
    } else {
        const int l = bx - 5120;
        w = w_out; wT = woT; K = DIM; N = DIM;
        n0 = (l % 32) * 32; k0 = (l / 32) * 32;
    }
    const int tx = threadIdx.x & 31;
    const int ty = threadIdx.x >> 5;
#pragma unroll
    for (int i = 0; i < 4; i++)
        t[ty + 8 * i][tx] = w[(size_t)(k0 + ty + 8 * i) * N + n0 + tx];
    __syncthreads();
#pragma unroll
    for (int i = 0; i < 4; i++)
        wT[(size_t)(n0 + ty + 8 * i) * K + k0 + tx] = f2bf(t[tx][ty + 8 * i]);
}

// ---------------------------------------------------------------------------
// bf16 head transpose (K only): in [bh, 64, 2048] -> out [bh, 2048, 64].
// ---------------------------------------------------------------------------
__global__ void transpose_head_k(const ushort_t* __restrict__ kin, ushort_t* __restrict__ kout) {
    __shared__ ushort_t t[32][33];
    const int tx = threadIdx.x & 31;
    const int ty = threadIdx.x >> 5;
    const int t0 = blockIdx.x * 32;
    const int d0 = blockIdx.y * 32;
    const int bh = blockIdx.z;
    const size_t base = (size_t)bh * DH * T_SEQ;
#pragma unroll
    for (int i = 0; i < 4; i++)
        t[ty + 8 * i][tx] = kin[base + (size_t)(d0 + ty + 8 * i) * T_SEQ + t0 + tx];
    __syncthreads();
#pragma unroll
    for (int i = 0; i < 4; i++)
        kout[base + (size_t)(t0 + ty + 8 * i) * DH + d0 + tx] = t[tx][ty + 8 * i];
}

// ---------------------------------------------------------------------------
// bf16 MFMA GEMM (verbatim r13/r15-verified). 128x128 tile, XCD swizzle.
// ---------------------------------------------------------------------------
template <int NN, int EPI>
__global__ __launch_bounds__(256) void gemm_bf16(
    const ushort_t* __restrict__ A, const ushort_t* __restrict__ Bt,
    float* __restrict__ C, ushort_t* __restrict__ qTt,
    ushort_t* __restrict__ kTt, ushort_t* __restrict__ vTt) {
    __shared__ short Sh[16384];
    short* As = Sh;
    short* Bs = Sh + 8192;
    const int tid = threadIdx.x;
    const int lane = tid & 63;
    const int l15 = lane & 15;
    const int l4 = lane >> 4;
    const int wid = tid >> 6;
    const int wr = wid >> 1;
    const int wc = wid & 1;
    const int nwg = gridDim.x * gridDim.y;
    const int lin = blockIdx.y * gridDim.x + blockIdx.x;
    const int swz = (lin & 7) * (nwg >> 3) + (lin >> 3);
    const int col0 = (swz % gridDim.x) * 128;
    const int row0 = (swz / gridDim.x) * 128;

    f32x4 acc[4][4];
#pragma unroll
    for (int mi = 0; mi < 4; mi++)
#pragma unroll
        for (int ni = 0; ni < 4; ni++) acc[mi][ni] = (f32x4)0.f;

    const int ldsbase = (tid & 192) * 8;

    for (int kt = 0; kt < 16; kt++) {
        const int k0 = kt * 64;
        if (kt) __syncthreads();
#pragma unroll
        for (int it = 0; it < 4; it++) {
            const int chunk = it * 256 + tid;
            const int row = chunk >> 3;
            const int c = chunk & 7;
            const int csrc = c ^ (row & 7);
            const ushort_t* ga = A + (size_t)(row0 + row) * 1024 + k0 + csrc * 8;
            __builtin_amdgcn_global_load_lds(
                (const AS1 void*)ga, (AS3 void*)(As + it * 2048 + ldsbase), 16, 0, 0);
            const ushort_t* gb = Bt + (size_t)(col0 + row) * 1024 + k0 + csrc * 8;
            __builtin_amdgcn_global_load_lds(
                (const AS1 void*)gb, (AS3 void*)(Bs + it * 2048 + ldsbase), 16, 0, 0);
        }
        __syncthreads();

#pragma unroll
        for (int ks = 0; ks < 2; ks++) {
            short8 af[4], bf[4];
#pragma unroll
            for (int mi = 0; mi < 4; mi++) {
                const int row = wr * 64 + mi * 16 + l15;
                const int c = (ks * 4 + l4) ^ (row & 7);
                af[mi] = *(const short8*)(As + row * 64 + c * 8);
            }
#pragma unroll
            for (int ni = 0; ni < 4; ni++) {
                const int row = wc * 64 + ni * 16 + l15;
                const int c = (ks * 4 + l4) ^ (row & 7);
                bf[ni] = *(const short8*)(Bs + row * 64 + c * 8);
            }
#pragma unroll
            for (int mi = 0; mi < 4; mi++)
#pragma unroll
                for (int ni = 0; ni < 4; ni++)
                    acc[mi][ni] = __builtin_amdgcn_mfma_f32_16x16x32_bf16(
                        af[mi], bf[ni], acc[mi][ni], 0, 0, 0);
        }
    }

    if (EPI == 0) {
#pragma unroll
        for (int mi = 0; mi < 4; mi++)
#pragma unroll
            for (int ni = 0; ni < 4; ni++) {
                const int col = col0 + wc * 64 + ni * 16 + l15;
#pragma unroll
                for (int reg = 0; reg < 4; reg++) {
                    const int row = row0 + wr * 64 + mi * 16 + l4 * 4 + reg;
                    C[(size_t)row * NN + col] = acc[mi][ni][reg];
                }
            }
    } else {
        __syncthreads();
#pragma unroll
        for (int ni = 0; ni < 4; ni++) {
            const int col = wc * 64 + ni * 16 + l15;
            const int gcol = col0 + col;
            const float sc = ((gcol % 48) < 16) ? 0.125f : 1.0f;  // q pre-scale
#pragma unroll
            for (int mi = 0; mi < 4; mi++)
#pragma unroll
                for (int reg = 0; reg < 4; reg++) {
                    const int row = wr * 64 + mi * 16 + l4 * 4 + reg;
                    Sh[col * 128 + (row ^ ((col & 7) << 3))] =
                        (short)f2bf(acc[mi][ni][reg] * sc);
                }
        }
        __syncthreads();
        const int b = row0 >> 11;
        const int tbase = row0 & 2047;
#pragma unroll
        for (int i = 0; i < 8; i++) {
            const int chunk = tid + 256 * i;
            const int col = chunk >> 4;
            const int r8 = chunk & 15;
            const short8 v =
                *(const short8*)(Sh + col * 128 + ((r8 * 8) ^ ((col & 7) << 3)));
            const int gcol = col0 + col;
            const int d = gcol / 48;
            const int rem = gcol % 48;
            const int kk = rem / 16;
            const int hh = rem % 16;
            ushort_t* dst = (kk == 0) ? qTt : (kk == 1) ? kTt : vTt;
            *(short8*)(dst + (((size_t)b * H + hh) * DH + d) * T_SEQ + tbase + r8 * 8) = v;
        }
    }
}

// ---------------------------------------------------------------------------
// MFMA flash attention (verbatim r17-verified). Fixed-max softmax, swapped
// QK^T: S^T = mfma(K-frag, Q-frag) -> lane holds P for one q-row (q=l15) at
// k = ni*16 + l4*4 + reg, which is exactly the K=16 MFMA A-frag layout, so
// cvt_pk pairs of exp(S) feed PV directly (no P LDS round-trip, no tr_read).
// 8 waves x 16 q-rows, 128-row double-buffered super-tiles, XCD swizzle.
// qTt pre-scaled 1/8 [b,h,d,t]; kT [b,h,t,64]; vTt [b,h,64,t].
// ---------------------------------------------------------------------------
__global__ __launch_bounds__(512) void attn_mfma(
    const ushort_t* __restrict__ qTt, const ushort_t* __restrict__ kT,
    const ushort_t* __restrict__ vTt, ushort_t* __restrict__ outB) {
    const int lin = blockIdx.z * 256 + blockIdx.y * 16 + blockIdx.x;
    const int swz = (lin & 7) * 64 + (lin >> 3);
    const int qt = swz & 15;
    const int hh = (swz >> 4) & 15;
    const int b  = swz >> 8;
    const int tid = threadIdx.x;       // 0..511
    const int lane = tid & 63;
    const int wid = tid >> 6;          // 0..7
    const int l15 = lane & 15;
    const int l4 = lane >> 4;

    __shared__ short Ks[2][2][4096];   // [buf][half][64 t x 64 d]
    __shared__ short Vs[2][2][4096];   // [buf][half][64 d x 64 t]

    const size_t hb  = ((size_t)b * H + hh) * T_SEQ * DH;
    const size_t hbT = ((size_t)b * H + hh) * (size_t)DH * T_SEQ;

    // Q fragments: 16 rows per wave, gathered from [b,h,d,t] (one-time)
    short8 qa[2];
    {
        const ushort_t* qb = qTt + hbT + (size_t)(qt * QBLK + wid * 16 + l15);
#pragma unroll
        for (int ks = 0; ks < 2; ks++)
#pragma unroll
            for (int j = 0; j < 8; j++)
                qa[ks][j] = (short)qb[(size_t)(ks * 32 + l4 * 8 + j) * T_SEQ];
    }

    f32x4 o[4];
#pragma unroll
    for (int nd = 0; nd < 4; nd++) o[nd] = (f32x4)0.f;
    float lsum = 0.f;

    const int ldsoff = (tid & 448) * 8;

    auto stage1 = [&](short* Kdst, short* Vdst, int t0) {
        const int row = tid >> 3;          // 0..63
        const int cs = (tid & 7) ^ (row & 7);
        __builtin_amdgcn_global_load_lds(
            (const AS1 void*)(kT + hb + (size_t)(t0 + row) * DH + cs * 8),
            (AS3 void*)(Kdst + ldsoff), 16, 0, 0);
        __builtin_amdgcn_global_load_lds(
            (const AS1 void*)(vTt + hbT + (size_t)row * T_SEQ + t0 + cs * 8),
            (AS3 void*)(Vdst + ldsoff), 16, 0, 0);
    };

    stage1(&Ks[0][0][0], &Vs[0][0][0], 0);
    stage1(&Ks[0][1][0], &Vs[0][1][0], 64);
    __syncthreads();
    int cur = 0;

    for (int jt2 = 0; jt2 < T_SEQ / 128; jt2++) {
        if (jt2 + 1 < T_SEQ / 128) {
            stage1(&Ks[cur ^ 1][0][0], &Vs[cur ^ 1][0][0], (jt2 + 1) * 128);
            stage1(&Ks[cur ^ 1][1][0], &Vs[cur ^ 1][1][0], (jt2 + 1) * 128 + 64);
        }

#pragma unroll
        for (int half = 0; half < 2; half++) {
            const short* Kb = &Ks[cur][half][0];
            const short* Vb = &Vs[cur][half][0];

            // ---- S^T = K Q^T (swapped operands) -------------------------
            f32x4 st[4];
#pragma unroll
            for (int ni = 0; ni < 4; ni++) st[ni] = (f32x4)0.f;
#pragma unroll
            for (int ks = 0; ks < 2; ks++) {
                short8 kb[4];
#pragma unroll
                for (int ni = 0; ni < 4; ni++) {
                    const int row = ni * 16 + l15;
                    const int rc = (ks * 4 + l4) ^ (row & 7);
                    kb[ni] = *(const short8*)(Kb + row * 64 + rc * 8);
                }
                __builtin_amdgcn_s_setprio(1);
#pragma unroll
                for (int ni = 0; ni < 4; ni++)
                    st[ni] = __builtin_amdgcn_mfma_f32_16x16x32_bf16(
                        kb[ni], qa[ks], st[ni], 0, 0, 0);
                __builtin_amdgcn_s_setprio(0);
            }

            // ---- P in-register: exp, lsum, cvt_pk -> PV A-frags ----------
            short4v pa[4];
#pragma unroll
            for (int ni = 0; ni < 4; ni++) {
                float p0 = __builtin_amdgcn_exp2f(__builtin_fmaf(st[ni][0], L2E, -SMAX * L2E));
                float p1 = __builtin_amdgcn_exp2f(__builtin_fmaf(st[ni][1], L2E, -SMAX * L2E));
                float p2 = __builtin_amdgcn_exp2f(__builtin_fmaf(st[ni][2], L2E, -SMAX * L2E));
                float p3 = __builtin_amdgcn_exp2f(__builtin_fmaf(st[ni][3], L2E, -SMAX * L2E));
                lsum += (p0 + p1) + (p2 + p3);
                uint_t lo, hi;
                asm("v_cvt_pk_bf16_f32 %0, %1, %2" : "=v"(lo) : "v"(p0), "v"(p1));
                asm("v_cvt_pk_bf16_f32 %0, %1, %2" : "=v"(hi) : "v"(p2), "v"(p3));
                union { uint_t u[2]; short4v s; } cv;
                cv.u[0] = lo; cv.u[1] = hi;
                pa[ni] = cv.s;
            }

            // ---- O += P V via K=16 MFMAs (A-frag = pa, zero shuffles) ----
#pragma unroll
            for (int ni = 0; ni < 4; ni++) {
                short4v vb[4];
#pragma unroll
                for (int nd = 0; nd < 4; nd++) {
                    const int row = nd * 16 + l15;
                    const int ch = (2 * ni + (l4 >> 1)) ^ (row & 7);
                    vb[nd] = *(const short4v*)(Vb + row * 64 + ch * 8 + (l4 & 1) * 4);
                }
                __builtin_amdgcn_s_setprio(1);
#pragma unroll
                for (int nd = 0; nd < 4; nd++)
                    o[nd] = MFMA16(pa[ni], vb[nd], o[nd]);
                __builtin_amdgcn_s_setprio(0);
            }
        }

        __syncthreads();
        cur ^= 1;
    }

    // ---- epilogue: reduce lsum across l4 groups, normalize, stage, store
    float tsum = lsum;
    tsum += __shfl_xor(tsum, 16);
    tsum += __shfl_xor(tsum, 32);
    // lane (l15, any l4) now holds full row-sum for q = l15
    short* Pt = ((short*)Ks) + wid * 1024;   // Ks dead after final barrier
#pragma unroll
    for (int reg = 0; reg < 4; reg++) {
        const int row = l4 * 4 + reg;
        const float inv = 1.0f / __shfl(tsum, row);
#pragma unroll
        for (int nd = 0; nd < 4; nd++)
            Pt[row * 64 + nd * 16 + l15] = (short)f2bf(o[nd][reg] * inv);
    }
    __syncthreads();
#pragma unroll
    for (int i = 0; i < 2; i++) {
        const int chunk = lane + 64 * i;     // 0..127
        const int row = chunk >> 3;
        const int c8 = (chunk & 7) * 8;
        const short8 vv = *(const short8*)(Pt + row * 64 + c8);
        *(short8*)(outB +
                   ((size_t)b * T_SEQ + (size_t)qt * QBLK + wid * 16 + row) * DIM +
                   hh * DH + c8) = vv;
    }
}

extern "C" void kernel_launch(void* const* d_in, const int* in_sizes, int n_in,
                              void* d_out, int out_size, void* d_ws, size_t ws_size,
                              hipStream_t stream) {
    const float* x     = (const float*)d_in[0];
    const float* w_qkv = (const float*)d_in[1];
    const float* w_out = (const float*)d_in[2];
    float* out = (float*)d_out;

    const size_t M = 4096;
    ushort_t* xb    = (ushort_t*)d_ws;                  // 4M shorts
    ushort_t* wqT   = xb + M * DIM;                     // 3M
    ushort_t* woT   = wqT + (size_t)D3 * DIM;           // 1M
    ushort_t* qTt   = woT + (size_t)DIM * DIM;          // 4M  [b,h,d,t] (q/8)
    ushort_t* kTt   = qTt + M * DIM;                    // 4M  [b,h,d,t]
    ushort_t* vTt   = kTt + M * DIM;                    // 4M  [b,h,d,t]
    ushort_t* kB    = vTt + M * DIM;                    // 4M  [b,h,t,d]
    ushort_t* attnB = kB + M * DIM;                     // 4M  [4096,1024]

    prep<<<dim3(6144), dim3(256), 0, stream>>>(x, xb, w_qkv, wqT, w_out, woT);

    gemm_bf16<D3, 1><<<dim3(D3 / 128, M / 128), dim3(256), 0, stream>>>(
        xb, wqT, nullptr, qTt, kTt, vTt);

    transpose_head_k<<<dim3(T_SEQ / 32, DH / 32, 32), dim3(256), 0, stream>>>(
        kTt, kB);

    attn_mfma<<<dim3(16, 16, 2), dim3(512), 0, stream>>>(
        qTt, kB, vTt, attnB);

    gemm_bf16<DIM, 0><<<dim3(DIM / 128, M / 128), dim3(256), 0, stream>>>(
        attnB, woT, out, nullptr, nullptr, nullptr);
}